// Round 2
// baseline (722.322 us; speedup 1.0000x reference)
//
#include <hip/hip_runtime.h>
#include <hip/hip_bf16.h>

#define N_NODES 50000
#define N_EDGES 800000
#define IN_N    256
#define D       64

typedef __attribute__((ext_vector_type(8))) short short8;
typedef __attribute__((ext_vector_type(4))) float f32x4;

__device__ __forceinline__ float bf2f(unsigned short h) {
    union { unsigned int u; float f; } x; x.u = ((unsigned int)h) << 16; return x.f;
}
__device__ __forceinline__ unsigned short f2bf(float f) {
    union { float f; unsigned int u; } x; x.f = f;
    unsigned int r = x.u + 0x7fff + ((x.u >> 16) & 1);   // RNE
    return (unsigned short)(r >> 16);
}
__device__ __forceinline__ short8 pack8(f32x4 p0, f32x4 p1) {
    short8 r;
    r[0] = (short)f2bf(p0[0]); r[1] = (short)f2bf(p0[1]);
    r[2] = (short)f2bf(p0[2]); r[3] = (short)f2bf(p0[3]);
    r[4] = (short)f2bf(p1[0]); r[5] = (short)f2bf(p1[1]);
    r[6] = (short)f2bf(p1[2]); r[7] = (short)f2bf(p1[3]);
    return r;
}

// histogram of incoming-edge counts per dst node
__global__ void count_kernel(const int* __restrict__ dst, int* __restrict__ count) {
    int i = blockIdx.x * blockDim.x + threadIdx.x;
    int stride = gridDim.x * blockDim.x;
    for (; i < N_EDGES / 4; i += stride) {
        int4 d = ((const int4*)dst)[i];
        atomicAdd(&count[d.x], 1);
        atomicAdd(&count[d.y], 1);
        atomicAdd(&count[d.z], 1);
        atomicAdd(&count[d.w], 1);
    }
}

// single-block exclusive scan over 50000 counts -> offsets[N+1], cursor copy
__global__ __launch_bounds__(1024) void scan_kernel(const int* __restrict__ count,
                                                    int* __restrict__ offsets,
                                                    int* __restrict__ cursor) {
    __shared__ int part[1024];
    const int t = threadIdx.x;
    const int C = (N_NODES + 1023) / 1024;        // 49 elements per thread
    const int base = t * C;
    int s = 0;
    for (int i = 0; i < C; ++i) {
        int idx = base + i;
        if (idx < N_NODES) s += count[idx];
    }
    part[t] = s;
    __syncthreads();
    for (int st = 1; st < 1024; st <<= 1) {       // Hillis-Steele inclusive scan
        int v = (t >= st) ? part[t - st] : 0;
        __syncthreads();
        part[t] += v;
        __syncthreads();
    }
    int run = part[t] - s;                        // exclusive base of this chunk
    for (int i = 0; i < C; ++i) {
        int idx = base + i;
        if (idx < N_NODES) {
            offsets[idx] = run;
            cursor[idx]  = run;
            run += count[idx];
        }
    }
    if (t == 1023) offsets[N_NODES] = part[1023];
}

// Prep: Wz = bf16(W_fc); Wu = bf16(W1 @ W_fc); Wv = bf16(W3 @ W_fc)  (all [64][256])
// Uses u = z@W1^T = x@(W1@W_fc)^T so the node pass shares A-fragments for z,u,v.
__global__ void prep_kernel(const float* __restrict__ W_fc, const float* __restrict__ W_e,
                            unsigned short* __restrict__ Wz,
                            unsigned short* __restrict__ Wu,
                            unsigned short* __restrict__ Wv)
{
    int flat = blockIdx.x * blockDim.x + threadIdx.x;   // 0..49151
    if (flat >= 3 * 64 * 256) return;
    int mat = flat >> 14;           // 16384 elems per matrix
    int idx = flat & 16383;
    if (mat == 0) {
        Wz[idx] = f2bf(W_fc[idx]);
        return;
    }
    int o = idx >> 8, i = idx & 255;
    const float* wrow = W_e + (size_t)o * 192 + (mat == 2 ? 128 : 0);
    float s = 0.f;
    #pragma unroll 8
    for (int j = 0; j < 64; ++j) s += wrow[j] * W_fc[(size_t)j * 256 + i];
    (mat == 1 ? Wu : Wv)[idx] = f2bf(s);
}

// Fused node pass: one sweep over nfeats produces z, u(+bias), v.
// LDS-free, barrier-free: b-fragments read straight from L2-resident Wz/Wu/Wv.
__global__ __launch_bounds__(256) void node_kernel(
    const float* __restrict__ nf,
    const unsigned short* __restrict__ Wz, const unsigned short* __restrict__ Wu,
    const unsigned short* __restrict__ Wv, const float* __restrict__ b_e,
    unsigned short* __restrict__ z_bf, unsigned short* __restrict__ u_bf,
    unsigned short* __restrict__ v_bf)
{
    const int lanelo = threadIdx.x & 15, quad = (threadIdx.x >> 4) & 3;
    float bias[4];
    #pragma unroll
    for (int t = 0; t < 4; ++t) bias[t] = b_e[t * 16 + lanelo];
    const int wflat = blockIdx.x * 4 + (threadIdx.x >> 6);
    const int nw = gridDim.x * 4;
    const f32x4 z4 = {0.f, 0.f, 0.f, 0.f};
    for (int g = wflat; g < N_NODES / 16; g += nw) {
        const int n0 = g * 16;
        f32x4 az[4] = {z4, z4, z4, z4};
        f32x4 au[4] = {z4, z4, z4, z4};
        f32x4 av[4] = {z4, z4, z4, z4};
        const float* arow = nf + (size_t)(n0 + lanelo) * IN_N;
        #pragma unroll
        for (int h = 0; h < 8; ++h) {
            const float* ap = arow + h * 32 + quad * 8;
            f32x4 p0 = *(const f32x4*)ap;
            f32x4 p1 = *(const f32x4*)(ap + 4);
            short8 a = pack8(p0, p1);
            const int bo = h * 32 + quad * 8;
            #pragma unroll
            for (int t = 0; t < 4; ++t) {
                const size_t rb = (size_t)(t * 16 + lanelo) * 256 + bo;
                az[t] = __builtin_amdgcn_mfma_f32_16x16x32_bf16(a, *(const short8*)&Wz[rb], az[t], 0, 0, 0);
                au[t] = __builtin_amdgcn_mfma_f32_16x16x32_bf16(a, *(const short8*)&Wu[rb], au[t], 0, 0, 0);
                av[t] = __builtin_amdgcn_mfma_f32_16x16x32_bf16(a, *(const short8*)&Wv[rb], av[t], 0, 0, 0);
            }
        }
        #pragma unroll
        for (int t = 0; t < 4; ++t)
            #pragma unroll
            for (int r = 0; r < 4; ++r) {
                const size_t row = (size_t)(n0 + quad * 4 + r) * D + t * 16 + lanelo;
                z_bf[row] = f2bf(az[t][r]);
                u_bf[row] = f2bf(au[t][r] + bias[t]);
                v_bf[row] = f2bf(av[t][r]);
            }
    }
}

// Fused edge pass: t = W2@efeat (MFMA); f = leaky(t+u[src]+v[dst]); feat_out = f;
// a = dot(f,w_c); ex = exp(a); scatter packed {ex,src} into dst-ordered CSR slot.
// efeats/feat_out use nontemporal ops: they are single-use streams, keep L2 for u/v gathers.
__global__ __launch_bounds__(256) void edge_kernel(
    const float* __restrict__ efeats,
    const int* __restrict__ src, const int* __restrict__ dst,
    const float* __restrict__ W_e, const float* __restrict__ w_c,
    const unsigned short* __restrict__ u_bf, const unsigned short* __restrict__ v_bf,
    int* __restrict__ cursor, unsigned long long* __restrict__ csr,
    float* __restrict__ feat_out)
{
    const int lanelo = threadIdx.x & 15, quad = (threadIdx.x >> 4) & 3;
    // W2 = W_e[:, 64:128].  b-frag: B[n=out=lanelo-tile][k=quad*8+j]
    short8 b2[4][2];
    #pragma unroll
    for (int t = 0; t < 4; ++t)
        #pragma unroll
        for (int h = 0; h < 2; ++h)
            #pragma unroll
            for (int j = 0; j < 8; ++j)
                b2[t][h][j] = (short)f2bf(W_e[(size_t)(t * 16 + lanelo) * 192 + 64 + h * 32 + quad * 8 + j]);
    float wcv[4];
    #pragma unroll
    for (int t = 0; t < 4; ++t) wcv[t] = w_c[t * 16 + lanelo];

    const int wflat = blockIdx.x * 4 + (threadIdx.x >> 6);
    const int nw = gridDim.x * 4;
    const f32x4 z4 = {0.f, 0.f, 0.f, 0.f};
    for (int g = wflat; g < N_EDGES / 16; g += nw) {
        const int e0 = g * 16;
        f32x4 acc[4] = {z4, z4, z4, z4};
        const float* ar = efeats + (size_t)(e0 + lanelo) * D;
        #pragma unroll
        for (int h = 0; h < 2; ++h) {
            f32x4 p0 = __builtin_nontemporal_load((const f32x4*)(ar + h * 32 + quad * 8));
            f32x4 p1 = __builtin_nontemporal_load((const f32x4*)(ar + h * 32 + quad * 8 + 4));
            short8 a = pack8(p0, p1);
            #pragma unroll
            for (int t = 0; t < 4; ++t)
                acc[t] = __builtin_amdgcn_mfma_f32_16x16x32_bf16(a, b2[t][h], acc[t], 0, 0, 0);
        }
        // this quad's 4 edges: e0 + quad*4 + r  (D row = quad*4+reg)
        int sn[4], dn[4];
        #pragma unroll
        for (int r = 0; r < 4; ++r) {
            sn[r] = src[e0 + quad * 4 + r];
            dn[r] = dst[e0 + quad * 4 + r];
        }
        float part[4];
        #pragma unroll
        for (int r = 0; r < 4; ++r) {
            float p = 0.f;
            #pragma unroll
            for (int t = 0; t < 4; ++t) {
                float f = acc[t][r]
                        + bf2f(u_bf[(size_t)sn[r] * D + t * 16 + lanelo])
                        + bf2f(v_bf[(size_t)dn[r] * D + t * 16 + lanelo]);
                f = f > 0.f ? f : 0.01f * f;
                __builtin_nontemporal_store(f, &feat_out[(size_t)(e0 + quad * 4 + r) * D + t * 16 + lanelo]);
                p += f * wcv[t];
            }
            part[r] = p;
        }
        #pragma unroll
        for (int st = 1; st < 16; st <<= 1) {
            #pragma unroll
            for (int r = 0; r < 4; ++r) part[r] += __shfl_xor(part[r], st, 64);
        }
        #pragma unroll
        for (int r = 0; r < 4; ++r) {
            float ex = __expf(part[r]);
            if (lanelo == 0) {
                int pos = atomicAdd(&cursor[dn[r]], 1);
                csr[pos] = ((unsigned long long)__float_as_uint(ex) << 32)
                         | (unsigned long long)(unsigned int)sn[r];
            }
        }
    }
}

// Gather aggregation: one wave per dst node. One coalesced 64-wide csr batch load,
// then shfl-broadcast entries with 4 independent z-row gathers per step (MLP).
__global__ __launch_bounds__(256) void agg_kernel(
    const unsigned long long* __restrict__ csr,
    const int* __restrict__ offsets,
    const unsigned short* __restrict__ z_bf,
    float* __restrict__ h)
{
    const int lane = threadIdx.x & 63;
    const int wid = (blockIdx.x * blockDim.x + threadIdx.x) >> 6;
    const int nw = (gridDim.x * blockDim.x) >> 6;
    for (int n = wid; n < N_NODES; n += nw) {
        const int off = offsets[n];
        const int d = offsets[n + 1] - off;
        float acc = 0.f, ssum = 0.f;
        for (int base = 0; base < d; base += 64) {
            const int cnt = min(d - base, 64);
            unsigned long long pk = csr[off + base + min(lane, cnt - 1)];
            unsigned int hi = (unsigned int)(pk >> 32);
            unsigned int lo = (unsigned int)pk;
            int j = 0;
            for (; j + 4 <= cnt; j += 4) {
                float x0 = __uint_as_float(__shfl((int)hi, j,     64));
                float x1 = __uint_as_float(__shfl((int)hi, j + 1, 64));
                float x2 = __uint_as_float(__shfl((int)hi, j + 2, 64));
                float x3 = __uint_as_float(__shfl((int)hi, j + 3, 64));
                int s0 = __shfl((int)lo, j,     64);
                int s1 = __shfl((int)lo, j + 1, 64);
                int s2 = __shfl((int)lo, j + 2, 64);
                int s3 = __shfl((int)lo, j + 3, 64);
                float z0 = bf2f(z_bf[(size_t)s0 * D + lane]);
                float z1 = bf2f(z_bf[(size_t)s1 * D + lane]);
                float z2 = bf2f(z_bf[(size_t)s2 * D + lane]);
                float z3 = bf2f(z_bf[(size_t)s3 * D + lane]);
                acc += x0 * z0; acc += x1 * z1; acc += x2 * z2; acc += x3 * z3;
                ssum += (x0 + x1) + (x2 + x3);
            }
            for (; j < cnt; ++j) {
                float xj = __uint_as_float(__shfl((int)hi, j, 64));
                int sj = __shfl((int)lo, j, 64);
                acc += xj * bf2f(z_bf[(size_t)sj * D + lane]);
                ssum += xj;
            }
        }
        h[(size_t)n * D + lane] = ssum > 0.f ? acc / ssum : 0.f;
    }
}

extern "C" void kernel_launch(void* const* d_in, const int* in_sizes, int n_in,
                              void* d_out, int out_size, void* d_ws, size_t ws_size,
                              hipStream_t stream)
{
    const float* nfeats = (const float*)d_in[0];
    const float* efeats = (const float*)d_in[1];
    const int* src = (const int*)d_in[2];
    const int* dst = (const int*)d_in[3];
    const float* W_fc = (const float*)d_in[4];
    const float* W_e  = (const float*)d_in[5];
    const float* b_e  = (const float*)d_in[6];
    const float* w_c  = (const float*)d_in[7];

    // ws: z_bf | u_bf | v_bf (bf16, 6.4MB each) | csr (8B*E = 6.4MB) |
    //     Wz|Wu|Wv (bf16 16384 each) | count | offsets | cursor  ~= 26.4MB
    unsigned short* z_bf = (unsigned short*)d_ws;
    unsigned short* u_bf = z_bf + (size_t)N_NODES * D;
    unsigned short* v_bf = u_bf + (size_t)N_NODES * D;
    unsigned long long* csr = (unsigned long long*)(v_bf + (size_t)N_NODES * D);
    unsigned short* Wz = (unsigned short*)(csr + (size_t)N_EDGES);
    unsigned short* Wu = Wz + 64 * 256;
    unsigned short* Wv = Wu + 64 * 256;
    int* count   = (int*)(Wv + 64 * 256);
    int* offsets = count + N_NODES;
    int* cursor  = offsets + N_NODES + 1;

    float* h_out = (float*)d_out;
    float* f_out = h_out + (size_t)N_NODES * D;

    hipMemsetAsync(count, 0, N_NODES * sizeof(int), stream);
    count_kernel<<<512, 256, 0, stream>>>(dst, count);
    scan_kernel<<<1, 1024, 0, stream>>>(count, offsets, cursor);
    prep_kernel<<<192, 256, 0, stream>>>(W_fc, W_e, Wz, Wu, Wv);
    node_kernel<<<782, 256, 0, stream>>>(nfeats, Wz, Wu, Wv, b_e, z_bf, u_bf, v_bf);
    edge_kernel<<<2048, 256, 0, stream>>>(efeats, src, dst, W_e, w_c, u_bf, v_bf,
                                          cursor, csr, f_out);
    agg_kernel<<<2048, 256, 0, stream>>>(csr, offsets, z_bf, h_out);
}